// Round 1
// baseline (28.131 us; speedup 1.0000x reference)
//
#include <hip/hip_runtime.h>

// Problem constants (fixed by setup_inputs):
//   B=32 batches, score map 128x128, images 3x512x512, region 70x70
//   img_stride = floor((512-70)/128) = 3
#define NB    32
#define SH    128
#define SW    128
#define IMG   512
#define REG   70
#define STRIDE_PX 3

// Per-crop element count: 32*3*70*70
#define NPER  470400
// Output offsets (elements) in flat d_out:
//   out0 fake_Br @0, out1 real_Ar @470400, out2 fake_Bf @940800,
//   out3 real_Af @1411200, out4 fake_ABf @1881600, out5 real_ABr @2822400
#define OFF_AB_F 1881600
#define OFF_AB_R 2822400

// Kernel 1: per-batch first-occurrence argmax/argmin over the 128x128 score map.
// Writes ws[b*4 + {0,1,2,3}] = {row0_real, col0_real, row0_fake, col0_fake}
// already scaled: idx*3 + 70 (or the vmax<=0 / vmin>=1 fallbacks).
__global__ void localize_kernel(const float* __restrict__ score, int* __restrict__ ws) {
    __shared__ float smax[256];
    __shared__ float smin[256];
    __shared__ int   jmax[256];
    __shared__ int   jmin[256];

    const int b = blockIdx.x;
    const int t = threadIdx.x;
    const float* s = score + (size_t)b * (SH * SW);

    float vmax = -__builtin_inff(); int ixmax = 0;
    float vmin =  __builtin_inff(); int ixmin = 0;
    // Strided scan: indices visited in increasing order per thread, so strict
    // comparisons preserve first-occurrence within a thread.
    for (int i = t; i < SH * SW; i += 256) {
        float v = s[i];
        if (v > vmax) { vmax = v; ixmax = i; }
        if (v < vmin) { vmin = v; ixmin = i; }
    }
    smax[t] = vmax; jmax[t] = ixmax;
    smin[t] = vmin; jmin[t] = ixmin;
    __syncthreads();

    // Tree reduction with smallest-index tie-break (row-major first occurrence).
    for (int off = 128; off > 0; off >>= 1) {
        if (t < off) {
            float ov = smax[t + off]; int oi = jmax[t + off];
            if (ov > smax[t] || (ov == smax[t] && oi < jmax[t])) { smax[t] = ov; jmax[t] = oi; }
            ov = smin[t + off]; oi = jmin[t + off];
            if (ov < smin[t] || (ov == smin[t] && oi < jmin[t])) { smin[t] = ov; jmin[t] = oi; }
        }
        __syncthreads();
    }

    if (t == 0) {
        int rrow, rcol, frow, fcol;
        if (smax[0] > 0.0f) { rrow = jmax[0] / SW; rcol = jmax[0] % SW; }
        else                { rrow = 0;            rcol = 0; }
        if (smin[0] < 1.0f) { frow = jmin[0] / SW; fcol = jmin[0] % SW; }
        else                { frow = 1;            fcol = 1; }
        ws[b * 4 + 0] = rrow * STRIDE_PX + 70;
        ws[b * 4 + 1] = rcol * STRIDE_PX + 70;
        ws[b * 4 + 2] = frow * STRIDE_PX + 70;
        ws[b * 4 + 3] = fcol * STRIDE_PX + 70;
    }
}

// Kernel 2: the 4 crops. Since crop origins are exact integers, bilinear
// degenerates to a gather with zero-fill where y>511 or x>511 (start>=70 so
// the lower bound never triggers). Each value is written to its primary
// output slot and to its slot inside the corresponding channel-concat output.
__global__ void crop_kernel(const float* __restrict__ fake_B,
                            const float* __restrict__ real_A,
                            const int* __restrict__ ws,
                            float* __restrict__ out) {
    int t = blockIdx.x * blockDim.x + threadIdx.x;
    if (t >= 4 * NPER) return;

    const int k  = t / NPER;          // 0:fake_Br 1:real_Ar 2:fake_Bf 3:real_Af
    const int r  = t % NPER;          // already [b,c,i,j] row-major
    const int b  = r / (3 * REG * REG);
    const int r2 = r % (3 * REG * REG);
    const int c  = r2 / (REG * REG);
    const int r3 = r2 % (REG * REG);
    const int i  = r3 / REG;
    const int j  = r3 % REG;

    const int* w = ws + b * 4;
    const int row0 = (k < 2) ? w[0] : w[2];
    const int col0 = (k < 2) ? w[1] : w[3];
    const int y = row0 + i;
    const int x = col0 + j;

    const float* src = (k == 0 || k == 2) ? fake_B : real_A;
    float v = 0.0f;
    if (y < IMG && x < IMG) {
        v = src[((size_t)b * 3 + c) * (IMG * IMG) + (size_t)y * IMG + x];
    }

    // Primary output: crops are laid out consecutively, same inner layout as r.
    out[(size_t)k * NPER + r] = v;

    // Concat output: fake_ABf = [real_Af | fake_Bf], real_ABr = [real_Ar | fake_Br].
    const size_t base = (k < 2) ? (size_t)OFF_AB_R : (size_t)OFF_AB_F;
    const int ch = (k == 1 || k == 3) ? c : (c + 3);   // B-crops go to channels 3..5
    out[base + ((size_t)b * 6 + ch) * (REG * REG) + i * REG + j] = v;
}

extern "C" void kernel_launch(void* const* d_in, const int* in_sizes, int n_in,
                              void* d_out, int out_size, void* d_ws, size_t ws_size,
                              hipStream_t stream) {
    // setup_inputs order: real_B, fake_B, real_A, score_map
    const float* fake_B    = (const float*)d_in[1];
    const float* real_A    = (const float*)d_in[2];
    const float* score_map = (const float*)d_in[3];
    float* out = (float*)d_out;
    int*   ws  = (int*)d_ws;

    localize_kernel<<<NB, 256, 0, stream>>>(score_map, ws);

    const int total = 4 * NPER;                 // 1,881,600
    const int blocks = (total + 255) / 256;     // 7350
    crop_kernel<<<blocks, 256, 0, stream>>>(fake_B, real_A, ws, out);
}

// Round 2
// 16.945 us; speedup vs baseline: 1.6602x; 1.6602x over previous
//
#include <hip/hip_runtime.h>

// Problem constants (fixed by setup_inputs):
//   B=32, score map 128x128, images 3x512x512, region 70x70, img_stride=3.
// Key facts: crop origins are exact integers (idx*3+70), so bilinear
// degenerates to a gather with zero-fill for y/x > 511. Score map (2 MB)
// fits in every XCD L2, so per-block redundant argmax/argmin re-reduction
// is ~free (L2 hits) and lets us fuse everything into ONE launch.
#define SSZ   16384            // 128*128
#define SW    128
#define IMG   512
#define REG   70
#define NPER  470400           // 32*3*70*70, one crop output
#define PER_PAIR_F2 7350       // 3*70*35 float2 per (crop,batch)
#define CHUNKS 4
#define F2_PER_CHUNK 1838      // ceil(7350/4)
#define OFF_AB_F 1881600       // fake_ABf base
#define OFF_AB_R 2822400       // real_ABr base

__global__ __launch_bounds__(256)
void fused_crop_kernel(const float* __restrict__ fake_B,
                       const float* __restrict__ real_A,
                       const float* __restrict__ score,
                       float* __restrict__ out) {
    const int blk   = blockIdx.x;
    const int pair  = blk / CHUNKS;     // 0..127 = k*32 + b
    const int chunk = blk % CHUNKS;
    const int k     = pair >> 5;        // 0:fake_Br 1:real_Ar 2:fake_Bf 3:real_Af
    const int b     = pair & 31;
    const int t     = threadIdx.x;

    // ---- Phase 1: redundant per-block argmax (k<2) or argmin (k>=2),
    //      first-occurrence semantics. 64 KB read, L2-resident. ----
    const bool needMax = (k < 2);
    const float4* s4 = (const float4*)(score + (size_t)b * SSZ);
    float best = needMax ? -__builtin_inff() : __builtin_inff();
    int bidx = 0;
    #pragma unroll
    for (int it = 0; it < 16; ++it) {
        const int q = it * 256 + t;     // increasing within thread -> strict
        const float4 v = s4[q];         //   compares keep first occurrence
        const int e = q * 4;
        if (needMax) {
            if (v.x > best) { best = v.x; bidx = e;     }
            if (v.y > best) { best = v.y; bidx = e + 1; }
            if (v.z > best) { best = v.z; bidx = e + 2; }
            if (v.w > best) { best = v.w; bidx = e + 3; }
        } else {
            if (v.x < best) { best = v.x; bidx = e;     }
            if (v.y < best) { best = v.y; bidx = e + 1; }
            if (v.z < best) { best = v.z; bidx = e + 2; }
            if (v.w < best) { best = v.w; bidx = e + 3; }
        }
    }
    // Wave butterfly reduce (lexicographic max over (v, -idx) / min over (v, idx)).
    #pragma unroll
    for (int off = 1; off < 64; off <<= 1) {
        const float ov = __shfl_xor(best, off);
        const int   oi = __shfl_xor(bidx, off);
        const bool take = needMax ? (ov > best || (ov == best && oi < bidx))
                                  : (ov < best || (ov == best && oi < bidx));
        if (take) { best = ov; bidx = oi; }
    }
    __shared__ float wv[4];
    __shared__ int   wi[4];
    __shared__ int   s_row0, s_col0;
    if ((t & 63) == 0) { wv[t >> 6] = best; wi[t >> 6] = bidx; }
    __syncthreads();
    if (t == 0) {
        float bv = wv[0]; int bi = wi[0];
        #pragma unroll
        for (int w = 1; w < 4; ++w) {
            const bool take = needMax ? (wv[w] > bv || (wv[w] == bv && wi[w] < bi))
                                      : (wv[w] < bv || (wv[w] == bv && wi[w] < bi));
            if (take) { bv = wv[w]; bi = wi[w]; }
        }
        int r, c;
        if (needMax) { if (bv > 0.0f) { r = bi / SW; c = bi % SW; } else { r = 0; c = 0; } }
        else         { if (bv < 1.0f) { r = bi / SW; c = bi % SW; } else { r = 1; c = 1; } }
        s_row0 = r * 3 + 70;
        s_col0 = c * 3 + 70;
    }
    __syncthreads();
    const int row0 = s_row0, col0 = s_col0;

    // ---- Phase 2: crop gather, float2 granularity (dest rows 8B-aligned),
    //      dual write: primary crop + channel-concat copy. ----
    const float* src = (k == 0 || k == 2) ? fake_B : real_A;
    const size_t srcb  = (size_t)b * 3 * IMG * IMG;
    const size_t prim  = (size_t)k * NPER + (size_t)b * 3 * 4900;
    const size_t cbase = ((k < 2) ? (size_t)OFF_AB_R : (size_t)OFF_AB_F)
                         + (size_t)b * 6 * 4900
                         + ((k == 1 || k == 3) ? 0 : 3) * 4900; // B-crops -> ch 3..5
    const int e0 = chunk * F2_PER_CHUNK;
    const int e1 = min(e0 + F2_PER_CHUNK, PER_PAIR_F2);
    for (int e = e0 + t; e < e1; e += 256) {
        const int c   = e / 2450;       // 70*35 float2 per channel
        const int rem = e % 2450;
        const int i   = rem / 35;
        const int jj  = rem % 35;
        const int y = row0 + i;
        const int x = col0 + 2 * jj;
        float2 v = make_float2(0.0f, 0.0f);
        if (y < IMG) {
            const float* p = src + srcb + (size_t)c * (IMG * IMG) + (size_t)y * IMG + x;
            if (x     < IMG) v.x = p[0];
            if (x + 1 < IMG) v.y = p[1];
        }
        const size_t inner = (size_t)c * 4900 + (size_t)i * 70 + 2 * jj;
        *(float2*)(out + prim  + inner) = v;
        *(float2*)(out + cbase + inner) = v;
    }
}

extern "C" void kernel_launch(void* const* d_in, const int* in_sizes, int n_in,
                              void* d_out, int out_size, void* d_ws, size_t ws_size,
                              hipStream_t stream) {
    // setup_inputs order: real_B, fake_B, real_A, score_map
    const float* fake_B    = (const float*)d_in[1];
    const float* real_A    = (const float*)d_in[2];
    const float* score_map = (const float*)d_in[3];
    float* out = (float*)d_out;

    const int blocks = 4 * 32 * CHUNKS;   // 512
    fused_crop_kernel<<<blocks, 256, 0, stream>>>(fake_B, real_A, score_map, out);
}